// Round 5
// baseline (304.833 us; speedup 1.0000x reference)
//
#include <hip/hip_runtime.h>

#define N_ATOMS 10000
#define N_EDGES 160000
#define N_STRUCT 8
#define PI_F 3.14159265358979323846f

// ---------------- setup kernels ----------------

__global__ void zero_kernel(int* cnt, float* accum) {
    int i = blockIdx.x * blockDim.x + threadIdx.x;
    if (i < N_ATOMS) cnt[i] = 0;
    if (i < N_STRUCT) accum[i] = 0.0f;
}

__global__ void hist_kernel(const int* __restrict__ receivers, int* __restrict__ cnt) {
    int e = blockIdx.x * blockDim.x + threadIdx.x;
    if (e < N_EDGES) atomicAdd(&cnt[receivers[e]], 1);
}

// exclusive scan of cnt -> row_ptr[0..N], also initializes cursor = row_ptr[0..N-1]
__global__ void scan_kernel(const int* __restrict__ cnt, int* __restrict__ row_ptr,
                            int* __restrict__ cursor) {
    __shared__ int buf[1024];
    __shared__ int carry;
    int t = threadIdx.x;
    if (t == 0) { carry = 0; row_ptr[0] = 0; cursor[0] = 0; }
    __syncthreads();
    for (int base = 0; base < N_ATOMS; base += 1024) {
        int x = (base + t < N_ATOMS) ? cnt[base + t] : 0;
        buf[t] = x;
        __syncthreads();
        for (int off = 1; off < 1024; off <<= 1) {
            int v = (t >= off) ? buf[t - off] : 0;
            __syncthreads();
            buf[t] += v;
            __syncthreads();
        }
        int inc = buf[t] + carry;
        if (base + t < N_ATOMS) {
            row_ptr[base + t + 1] = inc;
            if (base + t + 1 < N_ATOMS) cursor[base + t + 1] = inc;
        }
        __syncthreads();
        if (t == 1023) carry = inc;
        __syncthreads();
    }
}

// perm[e] = CSR slot for edge e (grouped by receiver)
__global__ void scatter_kernel(const int* __restrict__ receivers, int* __restrict__ cursor,
                               int* __restrict__ perm) {
    int e = blockIdx.x * blockDim.x + threadIdx.x;
    if (e < N_EDGES) perm[e] = atomicAdd(&cursor[receivers[e]], 1);
}

__global__ void emb_kernel(const float* __restrict__ embed, const int* __restrict__ species,
                           float* __restrict__ h0) {
    int i = blockIdx.x * blockDim.x + threadIdx.x;
    if (i < N_ATOMS * 16) {
        int a = i >> 4, c = i & 15;
        h0[i] = embed[species[a] * 16 + c];
    }
}

// gather h into CSR edge order: hs[slot][c] = h[snd_csr[slot]][c]
// one float4 per thread; 640k threads -> latency fully hidden
__global__ void gather_h(const int* __restrict__ snd_csr, const float* __restrict__ h,
                         float* __restrict__ hs) {
    int g = blockIdx.x * blockDim.x + threadIdx.x;
    if (g < N_EDGES * 4) {
        int slot = g >> 2, seg = g & 3;
        int s = snd_csr[slot];
        *(float4*)(hs + (size_t)slot * 16 + seg * 4) =
            *(const float4*)(h + (size_t)s * 16 + seg * 4);
    }
}

// ---------------- edge geometry, written in CSR (receiver-sorted) order ----------------

__global__ void edge_geom(const float* __restrict__ pos, const float* __restrict__ W_rad,
                          const int* __restrict__ senders, const int* __restrict__ receivers,
                          const int* __restrict__ perm,
                          float* __restrict__ sh_csr, float* __restrict__ R_csr,
                          int* __restrict__ snd_csr) {
    int e = blockIdx.x * blockDim.x + threadIdx.x;
    if (e >= N_EDGES) return;
    int s = senders[e], rc = receivers[e];
    int p = perm[e];
    float dx = pos[rc * 3 + 0] - pos[s * 3 + 0];
    float dy = pos[rc * 3 + 1] - pos[s * 3 + 1];
    float dz = pos[rc * 3 + 2] - pos[s * 3 + 2];
    float r = sqrtf(dx * dx + dy * dy + dz * dz);
    float rr = fmaxf(r, 1e-6f);
    float inv = 1.0f / rr;
    float x = dx * inv, y = dy * inv, z = dz * inv;
    float x2 = x * x, y2 = y * y, z2 = z * z;
    float she[16];
    she[0]  = 0.28209479f;
    she[1]  = 0.48860251f * y;
    she[2]  = 0.48860251f * z;
    she[3]  = 0.48860251f * x;
    she[4]  = 1.09254843f * x * y;
    she[5]  = 1.09254843f * y * z;
    she[6]  = 0.31539157f * (3.0f * z2 - 1.0f);
    she[7]  = 1.09254843f * x * z;
    she[8]  = 0.54627422f * (x2 - y2);
    she[9]  = 0.59004359f * y * (3.0f * x2 - y2);
    she[10] = 2.89061144f * x * y * z;
    she[11] = 0.45704579f * y * (5.0f * z2 - 1.0f);
    she[12] = 0.37317633f * z * (5.0f * z2 - 3.0f);
    she[13] = 0.45704579f * x * (5.0f * z2 - 1.0f);
    she[14] = 1.44530572f * z * (x2 - y2);
    she[15] = 0.59004359f * x * (x2 - 3.0f * y2);
    float4* shp = (float4*)(sh_csr + (size_t)p * 16);
    shp[0] = make_float4(she[0], she[1], she[2], she[3]);
    shp[1] = make_float4(she[4], she[5], she[6], she[7]);
    shp[2] = make_float4(she[8], she[9], she[10], she[11]);
    shp[3] = make_float4(she[12], she[13], she[14], she[15]);
    // radial: Bessel basis * cosine cutoff, projected by W_rad [4,8,4]
    float fc = 0.5f * (cosf(PI_F * fminf(r * 0.2f, 1.0f)) + 1.0f);
    const float c0 = 0.6324555320336759f; // sqrt(2/5)
    float bfv[8];
    #pragma unroll
    for (int n = 0; n < 8; ++n)
        bfv[n] = c0 * sinf((float)(n + 1) * PI_F * rr * 0.2f) * inv * fc;
    float Re[16];
    #pragma unroll
    for (int l = 0; l < 4; ++l) {
        #pragma unroll
        for (int n = 0; n < 4; ++n) {
            float acc = 0.0f;
            #pragma unroll
            for (int b = 0; b < 8; ++b) acc = fmaf(bfv[b], W_rad[l * 32 + b * 4 + n], acc);
            Re[l * 4 + n] = acc;
        }
    }
    float4* rp = (float4*)(R_csr + (size_t)p * 16);
    rp[0] = make_float4(Re[0], Re[1], Re[2], Re[3]);
    rp[1] = make_float4(Re[4], Re[5], Re[6], Re[7]);
    rp[2] = make_float4(Re[8], Re[9], Re[10], Re[11]);
    rp[3] = make_float4(Re[12], Re[13], Re[14], Re[15]);
    snd_csr[p] = s;
}

// ---------------- fused MP layer: ONE WAVE per atom, 4 atoms/block ----------------
// lane -> (m = lane>>2, cg = lane&3); regs hold A[m][n=0..3][c = cg*4 + j]
// Edge loop: three contiguous streams (sh, R, hs), no indirection, no branches:
// batches of 8 edges with clamped indices + zero-masked weight -> loads cluster,
// one waitcnt per batch instead of per edge.

__global__ __launch_bounds__(256, 4) void mp_layer(
    const int* __restrict__ row_ptr,
    const float* __restrict__ sh_csr, const float* __restrict__ R_csr,
    const float* __restrict__ hs,
    const float* __restrict__ W_inv,
    const float* __restrict__ cemb, float* __restrict__ h_out,
    const float* __restrict__ w_out, const float* __restrict__ comp_w,
    const int* __restrict__ species, const int* __restrict__ sids,
    float* __restrict__ accum, int do_energy)
{
    __shared__ float s_A[4][16 * 68 + 4];
    __shared__ float s_inv[4][256];
    __shared__ float s_red[4][16][16];

    const int t = threadIdx.x;
    const int w = t >> 6, lane = t & 63;
    const int atom = blockIdx.x * 4 + w;               // 2500*4 == 10000 exactly
    const int m = lane >> 2, cg = lane & 3;
    const int l = (m >= 9) ? 3 : (m >= 4) ? 2 : (m >= 1) ? 1 : 0;

    float acc[4][4];  // [n][j]
    #pragma unroll
    for (int n = 0; n < 4; ++n)
        #pragma unroll
        for (int j = 0; j < 4; ++j) acc[n][j] = 0.f;

    const int start = __builtin_amdgcn_readfirstlane(row_ptr[atom]);
    const int end   = __builtin_amdgcn_readfirstlane(row_ptr[atom + 1]);

    for (int base = start; base < end; base += 8) {
        float  slv[8];
        float4 rv[8], hv[8];
        #pragma unroll
        for (int q = 0; q < 8; ++q) {
            const int e = base + q;
            const int ec = (e < end) ? e : (end - 1);   // loop entered => end-1 >= start >= 0
            slv[q] = sh_csr[(size_t)ec * 16 + m];
            rv[q]  = *(const float4*)(R_csr + (size_t)ec * 16 + l * 4);
            hv[q]  = *(const float4*)(hs   + (size_t)ec * 16 + cg * 4);
        }
        #pragma unroll
        for (int q = 0; q < 8; ++q) {
            const int e = base + q;
            const float wmask = (e < end) ? slv[q] : 0.f;
            float hvj[4] = {hv[q].x, hv[q].y, hv[q].z, hv[q].w};
            float rvn[4] = {rv[q].x, rv[q].y, rv[q].z, rv[q].w};
            #pragma unroll
            for (int j = 0; j < 4; ++j) {
                float ww = wmask * hvj[j];
                #pragma unroll
                for (int n = 0; n < 4; ++n)
                    acc[n][j] = fmaf(ww, rvn[n], acc[n][j]);
            }
        }
    }

    // A -> LDS (own wave's strip only; same-wave DS is in-order, no barrier needed)
    #pragma unroll
    for (int n = 0; n < 4; ++n)
        *(float4*)&s_A[w][m * 68 + n * 16 + cg * 4] =
            make_float4(acc[n][0], acc[n][1], acc[n][2], acc[n][3]);

    // inv entries kt = lane*4+i, kt = l*64 + n*16 + c
    const float sc_l[4] = {1.0f, 0.57735026918962576f, 0.44721359549995794f, 0.37796447300922720f};
    float inv4[4];
    #pragma unroll
    for (int i = 0; i < 4; ++i) {
        const int kt = lane * 4 + i;
        const int le = kt >> 6, k64 = kt & 63;
        const int m0 = le * le, m1 = m0 + 2 * le;
        float s = 0.f;
        for (int mm = m0; mm <= m1; ++mm) {
            float v = s_A[w][mm * 68 + k64];
            s = fmaf(v, v, s);
        }
        inv4[i] = s * sc_l[le];
    }

    if (do_energy) {
        // e_atom = sum_k inv[k]*w_out[k] + comp_w[species]; wave-reduce, 0 barriers
        float s = 0.f;
        #pragma unroll
        for (int i = 0; i < 4; ++i) s = fmaf(inv4[i], w_out[lane * 4 + i], s);
        #pragma unroll
        for (int off = 32; off > 0; off >>= 1) s += __shfl_down(s, off);
        if (lane == 0) atomicAdd(&accum[sids[atom]], s + comp_w[species[atom]]);
    } else {
        *(float4*)&s_inv[w][lane * 4] = make_float4(inv4[0], inv4[1], inv4[2], inv4[3]);
        __syncthreads();
        // matvec: thread (c2 = t&15, g = t>>4) handles rows g*16..g*16+15 for all 4 atoms
        const int c2 = t & 15, g = t >> 4;
        float p[4] = {0.f, 0.f, 0.f, 0.f};
        #pragma unroll
        for (int jj4 = 0; jj4 < 4; ++jj4) {
            float4 iv[4];
            #pragma unroll
            for (int a = 0; a < 4; ++a)
                iv[a] = *(const float4*)&s_inv[a][g * 16 + jj4 * 4];
            #pragma unroll
            for (int u = 0; u < 4; ++u) {
                const int k = g * 16 + jj4 * 4 + u;
                float wv = W_inv[k * 16 + c2];
                p[0] = fmaf(((const float*)&iv[0])[u], wv, p[0]);
                p[1] = fmaf(((const float*)&iv[1])[u], wv, p[1]);
                p[2] = fmaf(((const float*)&iv[2])[u], wv, p[2]);
                p[3] = fmaf(((const float*)&iv[3])[u], wv, p[3]);
            }
        }
        #pragma unroll
        for (int a = 0; a < 4; ++a) s_red[a][g][c2] = p[a];
        __syncthreads();
        if (t < 64) {
            const int a = t >> 4, cc = t & 15;
            const int at = blockIdx.x * 4 + a;
            float s = 0.f;
            #pragma unroll
            for (int g2 = 0; g2 < 16; ++g2) s += s_red[a][g2][cc];
            h_out[at * 16 + cc] = s * cemb[at * 16 + cc];
        }
    }
}

__global__ void out_kernel(const float* __restrict__ accum, float* __restrict__ out) {
    int t = threadIdx.x;
    if (t < N_STRUCT) out[t] = accum[t];
}

// ---------------- launch ----------------

extern "C" void kernel_launch(void* const* d_in, const int* in_sizes, int n_in,
                              void* d_out, int out_size, void* d_ws, size_t ws_size,
                              hipStream_t stream) {
    const float* positions = (const float*)d_in[0];
    const float* embed     = (const float*)d_in[1];
    const float* W_rad     = (const float*)d_in[2];
    const float* W_inv1    = (const float*)d_in[3];
    const float* W_inv2    = (const float*)d_in[4];
    const float* w_out     = (const float*)d_in[5];
    const float* comp_w    = (const float*)d_in[6];
    const int* senders    = (const int*)d_in[7];
    const int* receivers  = (const int*)d_in[8];
    const int* species    = (const int*)d_in[9];
    const int* sids       = (const int*)d_in[10];
    float* out = (float*)d_out;

    char* ws = (char*)d_ws;
    size_t off = 0;
    auto alloc = [&](size_t bytes) -> void* {
        void* p = ws + off;
        off = (off + bytes + 255) & ~(size_t)255;
        return p;
    };
    float* sh_csr   = (float*)alloc((size_t)N_EDGES * 16 * 4);
    float* R_csr    = (float*)alloc((size_t)N_EDGES * 16 * 4);
    float* hs       = (float*)alloc((size_t)N_EDGES * 16 * 4);
    float* h0       = (float*)alloc((size_t)N_ATOMS * 16 * 4);
    float* h1       = (float*)alloc((size_t)N_ATOMS * 16 * 4);
    int*   cnt      = (int*)alloc((size_t)N_ATOMS * 4);
    int*   row_ptr  = (int*)alloc((size_t)(N_ATOMS + 1) * 4);
    int*   cursor   = (int*)alloc((size_t)N_ATOMS * 4);
    int*   perm     = (int*)alloc((size_t)N_EDGES * 4);
    int*   snd_csr  = (int*)alloc((size_t)N_EDGES * 4);
    float* accum    = (float*)alloc(8 * 4);

    const int EB = (N_EDGES + 255) / 256;        // 625
    const int AB = (N_ATOMS + 255) / 256;        // 40
    const int HB = (N_ATOMS * 16 + 255) / 256;   // 625
    const int GB = (N_EDGES * 4 + 255) / 256;    // 2500

    zero_kernel<<<AB, 256, 0, stream>>>(cnt, accum);
    hist_kernel<<<EB, 256, 0, stream>>>(receivers, cnt);
    scan_kernel<<<1, 1024, 0, stream>>>(cnt, row_ptr, cursor);
    scatter_kernel<<<EB, 256, 0, stream>>>(receivers, cursor, perm);
    edge_geom<<<EB, 256, 0, stream>>>(positions, W_rad, senders, receivers, perm,
                                      sh_csr, R_csr, snd_csr);
    emb_kernel<<<HB, 256, 0, stream>>>(embed, species, h0);

    // layer 1: h_in = cemb = h0, output h1
    gather_h<<<GB, 256, 0, stream>>>(snd_csr, h0, hs);
    mp_layer<<<N_ATOMS / 4, 256, 0, stream>>>(row_ptr, sh_csr, R_csr, hs,
                                              W_inv1, h0, h1,
                                              w_out, comp_w, species, sids, accum, 0);
    // layer 2: h_in = h1, energy path
    gather_h<<<GB, 256, 0, stream>>>(snd_csr, h1, hs);
    mp_layer<<<N_ATOMS / 4, 256, 0, stream>>>(row_ptr, sh_csr, R_csr, hs,
                                              W_inv2, h0, h1,
                                              w_out, comp_w, species, sids, accum, 1);

    out_kernel<<<1, 64, 0, stream>>>(accum, out);
}

// Round 6
// 298.920 us; speedup vs baseline: 1.0198x; 1.0198x over previous
//
#include <hip/hip_runtime.h>

#define N_ATOMS 10000
#define N_EDGES 160000
#define N_STRUCT 8
#define PI_F 3.14159265358979323846f

// per-edge packed record: floats [0..15]=sh, [16..31]=R(l-major), [32..47]=h[sender]
#define EDW 48   // words per edge (192 bytes)

// async global->LDS DMA: each lane deposits 16B at ldsbase + lane*16  [m97/m104]
__device__ __forceinline__ void load_lds16(const float* g, float* l) {
    __builtin_amdgcn_global_load_lds(
        (const __attribute__((address_space(1))) void*)g,
        (__attribute__((address_space(3))) void*)l,
        16, 0, 0);
}

// ---------------- setup kernels ----------------

__global__ void zero_kernel(int* cnt, float* accum) {
    int i = blockIdx.x * blockDim.x + threadIdx.x;
    if (i < N_ATOMS) cnt[i] = 0;
    if (i < N_STRUCT) accum[i] = 0.0f;
}

__global__ void hist_kernel(const int* __restrict__ receivers, int* __restrict__ cnt) {
    int e = blockIdx.x * blockDim.x + threadIdx.x;
    if (e < N_EDGES) atomicAdd(&cnt[receivers[e]], 1);
}

// exclusive scan of cnt -> row_ptr[0..N], also initializes cursor
__global__ void scan_kernel(const int* __restrict__ cnt, int* __restrict__ row_ptr,
                            int* __restrict__ cursor) {
    __shared__ int buf[1024];
    __shared__ int carry;
    int t = threadIdx.x;
    if (t == 0) { carry = 0; row_ptr[0] = 0; cursor[0] = 0; }
    __syncthreads();
    for (int base = 0; base < N_ATOMS; base += 1024) {
        int x = (base + t < N_ATOMS) ? cnt[base + t] : 0;
        buf[t] = x;
        __syncthreads();
        for (int off = 1; off < 1024; off <<= 1) {
            int v = (t >= off) ? buf[t - off] : 0;
            __syncthreads();
            buf[t] += v;
            __syncthreads();
        }
        int inc = buf[t] + carry;
        if (base + t < N_ATOMS) {
            row_ptr[base + t + 1] = inc;
            if (base + t + 1 < N_ATOMS) cursor[base + t + 1] = inc;
        }
        __syncthreads();
        if (t == 1023) carry = inc;
        __syncthreads();
    }
}

__global__ void scatter_kernel(const int* __restrict__ receivers, int* __restrict__ cursor,
                               int* __restrict__ perm) {
    int e = blockIdx.x * blockDim.x + threadIdx.x;
    if (e < N_EDGES) perm[e] = atomicAdd(&cursor[receivers[e]], 1);
}

__global__ void emb_kernel(const float* __restrict__ embed, const int* __restrict__ species,
                           float* __restrict__ h0) {
    int i = blockIdx.x * blockDim.x + threadIdx.x;
    if (i < N_ATOMS * 16) {
        int a = i >> 4, c = i & 15;
        h0[i] = embed[species[a] * 16 + c];
    }
}

// gather h into edat[slot][32..47]
__global__ void gather_h(const int* __restrict__ snd_csr, const float* __restrict__ h,
                         float* __restrict__ edat) {
    int g = blockIdx.x * blockDim.x + threadIdx.x;
    if (g < N_EDGES * 4) {
        int slot = g >> 2, seg = g & 3;
        int s = snd_csr[slot];
        *(float4*)(edat + (size_t)slot * EDW + 32 + seg * 4) =
            *(const float4*)(h + (size_t)s * 16 + seg * 4);
    }
}

// ---------------- edge geometry -> edat[slot][0..31], CSR order ----------------

__global__ void edge_geom(const float* __restrict__ pos, const float* __restrict__ W_rad,
                          const int* __restrict__ senders, const int* __restrict__ receivers,
                          const int* __restrict__ perm,
                          float* __restrict__ edat, int* __restrict__ snd_csr) {
    int e = blockIdx.x * blockDim.x + threadIdx.x;
    if (e >= N_EDGES) return;
    int s = senders[e], rc = receivers[e];
    int p = perm[e];
    float dx = pos[rc * 3 + 0] - pos[s * 3 + 0];
    float dy = pos[rc * 3 + 1] - pos[s * 3 + 1];
    float dz = pos[rc * 3 + 2] - pos[s * 3 + 2];
    float r = sqrtf(dx * dx + dy * dy + dz * dz);
    float rr = fmaxf(r, 1e-6f);
    float inv = 1.0f / rr;
    float x = dx * inv, y = dy * inv, z = dz * inv;
    float x2 = x * x, y2 = y * y, z2 = z * z;
    float she[16];
    she[0]  = 0.28209479f;
    she[1]  = 0.48860251f * y;
    she[2]  = 0.48860251f * z;
    she[3]  = 0.48860251f * x;
    she[4]  = 1.09254843f * x * y;
    she[5]  = 1.09254843f * y * z;
    she[6]  = 0.31539157f * (3.0f * z2 - 1.0f);
    she[7]  = 1.09254843f * x * z;
    she[8]  = 0.54627422f * (x2 - y2);
    she[9]  = 0.59004359f * y * (3.0f * x2 - y2);
    she[10] = 2.89061144f * x * y * z;
    she[11] = 0.45704579f * y * (5.0f * z2 - 1.0f);
    she[12] = 0.37317633f * z * (5.0f * z2 - 3.0f);
    she[13] = 0.45704579f * x * (5.0f * z2 - 1.0f);
    she[14] = 1.44530572f * z * (x2 - y2);
    she[15] = 0.59004359f * x * (x2 - 3.0f * y2);
    float* ed = edat + (size_t)p * EDW;
    ((float4*)ed)[0] = make_float4(she[0], she[1], she[2], she[3]);
    ((float4*)ed)[1] = make_float4(she[4], she[5], she[6], she[7]);
    ((float4*)ed)[2] = make_float4(she[8], she[9], she[10], she[11]);
    ((float4*)ed)[3] = make_float4(she[12], she[13], she[14], she[15]);
    float fc = 0.5f * (cosf(PI_F * fminf(r * 0.2f, 1.0f)) + 1.0f);
    const float c0 = 0.6324555320336759f; // sqrt(2/5)
    float bfv[8];
    #pragma unroll
    for (int n = 0; n < 8; ++n)
        bfv[n] = c0 * sinf((float)(n + 1) * PI_F * rr * 0.2f) * inv * fc;
    float Re[16];
    #pragma unroll
    for (int l = 0; l < 4; ++l) {
        #pragma unroll
        for (int n = 0; n < 4; ++n) {
            float acc = 0.0f;
            #pragma unroll
            for (int b = 0; b < 8; ++b) acc = fmaf(bfv[b], W_rad[l * 32 + b * 4 + n], acc);
            Re[l * 4 + n] = acc;
        }
    }
    ((float4*)ed)[4] = make_float4(Re[0], Re[1], Re[2], Re[3]);
    ((float4*)ed)[5] = make_float4(Re[4], Re[5], Re[6], Re[7]);
    ((float4*)ed)[6] = make_float4(Re[8], Re[9], Re[10], Re[11]);
    ((float4*)ed)[7] = make_float4(Re[12], Re[13], Re[14], Re[15]);
    snd_csr[p] = s;
}

// ---------------- fused MP layer: one wave per atom, 4 atoms/block ----------------
// Edge loop: 16-edge chunk (3 KB) staged via 3x global_load_lds dwordx4 (1 KB each),
// one vmcnt(0) drain per chunk, broadcast ds_reads for compute. No barriers.

__global__ __launch_bounds__(256) void mp_layer(
    const int* __restrict__ row_ptr, const float* __restrict__ edat,
    const float* __restrict__ W_inv,
    const float* __restrict__ cemb, float* __restrict__ h_out,
    const float* __restrict__ w_out, const float* __restrict__ comp_w,
    const int* __restrict__ species, const int* __restrict__ sids,
    float* __restrict__ accum, int do_energy)
{
    __shared__ __attribute__((aligned(16))) float stage[4][768]; // 3 KB per wave
    __shared__ float s_A[4][16 * 68 + 4];
    __shared__ float s_inv[4][256];
    __shared__ float s_red[4][16][16];

    const int t = threadIdx.x;
    const int w = t >> 6, lane = t & 63;
    const int atom = blockIdx.x * 4 + w;               // 2500*4 == 10000 exactly
    const int m = lane >> 2, cg = lane & 3;
    const int l = (m >= 9) ? 3 : (m >= 4) ? 2 : (m >= 1) ? 1 : 0;

    float acc[4][4];  // [n][j]
    #pragma unroll
    for (int n = 0; n < 4; ++n)
        #pragma unroll
        for (int j = 0; j < 4; ++j) acc[n][j] = 0.f;

    const int start = row_ptr[atom];
    const int end   = row_ptr[atom + 1];
    const char* gbase = (const char*)edat;
    const long long maxb = (long long)end * (EDW * 4) - 16;

    for (int c0 = start; c0 < end; c0 += 16) {
        // drain our own ds_reads of the previous chunk before DMA overwrites the strip
        __builtin_amdgcn_s_waitcnt(0xC07F);   // lgkmcnt(0) only
        #pragma unroll
        for (int i = 0; i < 3; ++i) {
            long long gb = (long long)c0 * (EDW * 4) + i * 1024 + lane * 16;
            if (gb > maxb) gb = maxb;        // clamp: duplicates of last edge, never read
            load_lds16((const float*)(gbase + gb), &stage[w][i * 256]);
        }
        __builtin_amdgcn_s_waitcnt(0x0F70);   // vmcnt(0) only
        __builtin_amdgcn_sched_barrier(0);

        const int nb = min(16, end - c0);
        for (int q = 0; q < nb; ++q) {
            const float* eq = &stage[w][q * EDW];
            float shv = eq[m];                                   // broadcast ds_read
            float4 rv = *(const float4*)(eq + 16 + l * 4);       // broadcast b128
            float4 hv = *(const float4*)(eq + 32 + cg * 4);      // broadcast b128
            float hvj[4] = {hv.x, hv.y, hv.z, hv.w};
            float rvn[4] = {rv.x, rv.y, rv.z, rv.w};
            #pragma unroll
            for (int j = 0; j < 4; ++j) {
                float ww = shv * hvj[j];
                #pragma unroll
                for (int n = 0; n < 4; ++n)
                    acc[n][j] = fmaf(ww, rvn[n], acc[n][j]);
            }
        }
        __builtin_amdgcn_sched_barrier(0);
    }

    // A -> LDS (own wave's strip; same-wave DS in-order, no barrier)
    #pragma unroll
    for (int n = 0; n < 4; ++n)
        *(float4*)&s_A[w][m * 68 + n * 16 + cg * 4] =
            make_float4(acc[n][0], acc[n][1], acc[n][2], acc[n][3]);

    const float sc_l[4] = {1.0f, 0.57735026918962576f, 0.44721359549995794f, 0.37796447300922720f};
    float inv4[4];
    #pragma unroll
    for (int i = 0; i < 4; ++i) {
        const int kt = lane * 4 + i;
        const int le = kt >> 6, k64 = kt & 63;
        const int m0 = le * le, m1 = m0 + 2 * le;
        float s = 0.f;
        for (int mm = m0; mm <= m1; ++mm) {
            float v = s_A[w][mm * 68 + k64];
            s = fmaf(v, v, s);
        }
        inv4[i] = s * sc_l[le];
    }

    if (do_energy) {
        float s = 0.f;
        #pragma unroll
        for (int i = 0; i < 4; ++i) s = fmaf(inv4[i], w_out[lane * 4 + i], s);
        #pragma unroll
        for (int off = 32; off > 0; off >>= 1) s += __shfl_down(s, off);
        if (lane == 0) atomicAdd(&accum[sids[atom]], s + comp_w[species[atom]]);
    } else {
        *(float4*)&s_inv[w][lane * 4] = make_float4(inv4[0], inv4[1], inv4[2], inv4[3]);
        __syncthreads();
        const int c2 = t & 15, g = t >> 4;
        float p[4] = {0.f, 0.f, 0.f, 0.f};
        #pragma unroll
        for (int jj4 = 0; jj4 < 4; ++jj4) {
            float4 iv[4];
            #pragma unroll
            for (int a = 0; a < 4; ++a)
                iv[a] = *(const float4*)&s_inv[a][g * 16 + jj4 * 4];
            #pragma unroll
            for (int u = 0; u < 4; ++u) {
                const int k = g * 16 + jj4 * 4 + u;
                float wv = W_inv[k * 16 + c2];
                p[0] = fmaf(((const float*)&iv[0])[u], wv, p[0]);
                p[1] = fmaf(((const float*)&iv[1])[u], wv, p[1]);
                p[2] = fmaf(((const float*)&iv[2])[u], wv, p[2]);
                p[3] = fmaf(((const float*)&iv[3])[u], wv, p[3]);
            }
        }
        #pragma unroll
        for (int a = 0; a < 4; ++a) s_red[a][g][c2] = p[a];
        __syncthreads();
        if (t < 64) {
            const int a = t >> 4, cc = t & 15;
            const int at = blockIdx.x * 4 + a;
            float s = 0.f;
            #pragma unroll
            for (int g2 = 0; g2 < 16; ++g2) s += s_red[a][g2][cc];
            h_out[at * 16 + cc] = s * cemb[at * 16 + cc];
        }
    }
}

__global__ void out_kernel(const float* __restrict__ accum, float* __restrict__ out) {
    int t = threadIdx.x;
    if (t < N_STRUCT) out[t] = accum[t];
}

// ---------------- launch ----------------

extern "C" void kernel_launch(void* const* d_in, const int* in_sizes, int n_in,
                              void* d_out, int out_size, void* d_ws, size_t ws_size,
                              hipStream_t stream) {
    const float* positions = (const float*)d_in[0];
    const float* embed     = (const float*)d_in[1];
    const float* W_rad     = (const float*)d_in[2];
    const float* W_inv1    = (const float*)d_in[3];
    const float* W_inv2    = (const float*)d_in[4];
    const float* w_out     = (const float*)d_in[5];
    const float* comp_w    = (const float*)d_in[6];
    const int* senders    = (const int*)d_in[7];
    const int* receivers  = (const int*)d_in[8];
    const int* species    = (const int*)d_in[9];
    const int* sids       = (const int*)d_in[10];
    float* out = (float*)d_out;

    char* ws = (char*)d_ws;
    size_t off = 0;
    auto alloc = [&](size_t bytes) -> void* {
        void* p = ws + off;
        off = (off + bytes + 255) & ~(size_t)255;
        return p;
    };
    float* edat     = (float*)alloc((size_t)N_EDGES * EDW * 4);
    float* h0       = (float*)alloc((size_t)N_ATOMS * 16 * 4);
    float* h1       = (float*)alloc((size_t)N_ATOMS * 16 * 4);
    int*   cnt      = (int*)alloc((size_t)N_ATOMS * 4);
    int*   row_ptr  = (int*)alloc((size_t)(N_ATOMS + 1) * 4);
    int*   cursor   = (int*)alloc((size_t)N_ATOMS * 4);
    int*   perm     = (int*)alloc((size_t)N_EDGES * 4);
    int*   snd_csr  = (int*)alloc((size_t)N_EDGES * 4);
    float* accum    = (float*)alloc(8 * 4);

    const int EB = (N_EDGES + 255) / 256;        // 625
    const int AB = (N_ATOMS + 255) / 256;        // 40
    const int HB = (N_ATOMS * 16 + 255) / 256;   // 625
    const int GB = (N_EDGES * 4 + 255) / 256;    // 2500

    zero_kernel<<<AB, 256, 0, stream>>>(cnt, accum);
    hist_kernel<<<EB, 256, 0, stream>>>(receivers, cnt);
    scan_kernel<<<1, 1024, 0, stream>>>(cnt, row_ptr, cursor);
    scatter_kernel<<<EB, 256, 0, stream>>>(receivers, cursor, perm);
    edge_geom<<<EB, 256, 0, stream>>>(positions, W_rad, senders, receivers, perm,
                                      edat, snd_csr);
    emb_kernel<<<HB, 256, 0, stream>>>(embed, species, h0);

    // layer 1
    gather_h<<<GB, 256, 0, stream>>>(snd_csr, h0, edat);
    mp_layer<<<N_ATOMS / 4, 256, 0, stream>>>(row_ptr, edat,
                                              W_inv1, h0, h1,
                                              w_out, comp_w, species, sids, accum, 0);
    // layer 2 (energy)
    gather_h<<<GB, 256, 0, stream>>>(snd_csr, h1, edat);
    mp_layer<<<N_ATOMS / 4, 256, 0, stream>>>(row_ptr, edat,
                                              W_inv2, h0, h1,
                                              w_out, comp_w, species, sids, accum, 1);

    out_kernel<<<1, 64, 0, stream>>>(accum, out);
}